// Round 6
// baseline (127.180 us; speedup 1.0000x reference)
//
#include <hip/hip_runtime.h>

// ---------------- problem constants (from setup_inputs) ----------------
static constexpr int Bn = 16, Kn = 50, NCn = 80;
// scales: s=0 -> o1 (13x13, anchors[6:9]), s=1 -> o2 (26x26, anchors[3:6]),
//         s=2 -> o3 (52x52, anchors[0:3])
static constexpr int NTOT = 16 * 3 * (169 + 676 + 2704);   // 170352 cells
static constexpr int NBLK_A = (NTOT + 255) / 256;          // 666
static constexpr int NBLK_ASSIGN = 12;                     // 48 waves, 1 per (s,b)
static constexpr int NREC = 3 * Bn * Kn;                   // 2400 records
static constexpr int NBLK_F = NREC / 4;                    // 600 blocks, 4 waves ea
// ws layout (float/int elements) — NOTHING needs pre-zeroing (poison-safe):
static constexpr int MIOU_OFF = 0;                 // 170352 floats, all written
static constexpr int NO_OFF   = 170352;            // 16 ints, all written
static constexpr int REC_OFF  = 170368;            // 2400 x 8 floats, all written
static constexpr int EXPC_OFF = 189568;            // 666 ints: export count/block
static constexpr int EXPD_OFF = 190240;            // 666 x 16 floats: exports
static constexpr int CNT_OFF  = 200896;            // 1 int: done ticket (K1 zeroes)
static constexpr int ACC_OFF  = 200897;            // 1 float: loss acc (K1 zeroes)
static constexpr float IGN = 0.7f;
static constexpr float W_BOX = 1.0f / 96.0f;  // 0.5 / (B*3)
static constexpr float W_IOU = 1.0f / 96.0f;  // 0.5 / (B*3)
static constexpr float W_CLS = 1.0f / 48.0f;  // 1.0 / (B*3)

__device__ __forceinline__ float sigf(float x) { return 1.0f / (1.0f + __expf(-x)); }

__device__ __forceinline__ float iou_box(float ax, float ay, float aw, float ah,
                                         float bx, float by, float bw, float bh) {
  float tlx = fmaxf(ax - aw * 0.5f, bx - bw * 0.5f);
  float tly = fmaxf(ay - ah * 0.5f, by - bh * 0.5f);
  float brx = fminf(ax + aw * 0.5f, bx + bw * 0.5f);
  float bry = fminf(ay + ah * 0.5f, by + bh * 0.5f);
  float w = fmaxf(brx - tlx, 0.0f);
  float h = fmaxf(bry - tly, 0.0f);
  float inter = w * h;
  float uni = aw * ah + bw * bh - inter;
  return inter / uni;
}

__device__ __forceinline__ void decode_cell(int g, int& s, int& H, int& HW,
                                            int& base, int& b, int& a, int& hw) {
  if (g < 8112)       { s = 0; H = 13; HW = 169;  base = 0; }
  else if (g < 40560) { s = 1; H = 26; HW = 676;  base = 8112; }
  else                { s = 2; H = 52; HW = 2704; base = 40560; }
  int local = g - base;
  hw = local % HW;
  int t = local / HW;
  a = t % 3;
  b = t / 3;
}

// ---- kMain ----
// blocks [0, NBLK_A): per-cell max-IoU (corner-form targets, cross-mult max,
//   one div) + LDS noobj partials exported compacted per block.
// blocks [NBLK_A, NBLK_A+12): target assignment, one wave per (scale,batch);
//   block NBLK_A also zero-inits K2's ticket + accumulator.
__global__ __launch_bounds__(256) void kMain(const float* __restrict__ o0,
                                             const float* __restrict__ o1,
                                             const float* __restrict__ o2,
                                             const float* __restrict__ tgt,
                                             const float* __restrict__ anc,
                                             float* __restrict__ ws) {
  __shared__ float tg[Bn * Kn * 5];      // raw targets (assignment path)
  __shared__ float4 tga[Bn * Kn];        // corner-form  (per-cell path)
  __shared__ float  tgb[Bn * Kn];        // valid? area : -1
  __shared__ float ls1[48], ls2[48], lhp[48];
  __shared__ int lcnt;
  int tid = threadIdx.x;

  if (blockIdx.x >= NBLK_A) {
    // ---- parallel target assignment ----
    for (int i = tid; i < Bn * Kn * 5; i += 256) tg[i] = tgt[i];
    if (blockIdx.x == NBLK_A && tid == 0) {
      ((int*)ws)[CNT_OFF] = 0;           // K2 ticket
      ws[ACC_OFF] = 0.0f;                // K2 accumulator
    }
    __syncthreads();
    int wv = (blockIdx.x - NBLK_A) * 4 + (tid >> 6);  // 0..47 = (s,b)
    int lane = tid & 63;
    int s = wv / 16, b = wv % 16;
    int H, HW, base;
    if (s == 0)      { H = 13; HW = 169;  base = 0; }
    else if (s == 1) { H = 26; HW = 676;  base = 8112; }
    else             { H = 52; HW = 2704; base = 40560; }
    int W = H;
    int aoff = 6 - 3 * s;
    float aw0 = anc[aoff * 2],       ah0 = anc[aoff * 2 + 1];
    float aw1 = anc[(aoff + 1) * 2], ah1 = anc[(aoff + 1) * 2 + 1];
    float aw2 = anc[(aoff + 2) * 2], ah2 = anc[(aoff + 2) * 2 + 1];

    bool valid = false;
    int gslot = -1 - lane;                  // unique sentinel for invalid lanes
    float dx = 0, dy = 0, dw = 0, dh = 0, tc = 0;
    if (lane < Kn) {
      const float* tp = &tg[(b * Kn + lane) * 5];
      float tx = tp[0], ty = tp[1], tw = tp[2], th = tp[3];
      tc = tp[4];
      if (tx + ty + tw + th + tc > 0.0f) {
        valid = true;
        float gx = tx * W, gy = ty * H, gw = tw * W, gh = th * H;
        int cx = (int)floorf(gx); cx = min(max(cx, 0), W - 1);
        int cy = (int)floorf(gy); cy = min(max(cy, 0), H - 1);
        float ccx = cx + 0.5f, ccy = cy + 0.5f;
        float i0 = iou_box(ccx, ccy, aw0, ah0, gx, gy, gw, gh);
        float i1 = iou_box(ccx, ccy, aw1, ah1, gx, gy, gw, gh);
        float i2 = iou_box(ccx, ccy, aw2, ah2, gx, gy, gw, gh);
        int astar = 0; float bi = i0;
        if (i1 > bi) { bi = i1; astar = 1; }   // strict > == argmax first-max
        if (i2 > bi) { bi = i2; astar = 2; }
        float raw = (astar == 0) ? aw0 : (astar == 1) ? aw1 : aw2;
        float rah = (astar == 0) ? ah0 : (astar == 1) ? ah1 : ah2;
        gslot = base + (b * 3 + astar) * HW + cy * W + cx;
        dx = gx - (float)cx;
        dy = gy - (float)cy;
        dw = gw / raw;
        dh = gh / rah;
      }
    }
    // winner = valid and no valid lane k2 > lane targeting the same slot
    // (== jax segment_max over global rank: slots never collide across b/s)
    bool win = valid;
    for (int k2 = 1; k2 < Kn; k2++) {
      int other = __shfl(gslot, k2);
      if (k2 > lane && other == gslot) win = false;
    }
    unsigned long long bal = __ballot(valid);
    if (lane == 0 && s == 0) ((int*)ws)[NO_OFF + b] = (int)__popcll(bal);
    if (lane < Kn) {
      float* r = ws + REC_OFF + (size_t)(wv * Kn + lane) * 8;
      r[0] = win ? 1.0f : 0.0f;
      r[1] = __int_as_float(gslot);
      r[2] = dx; r[3] = dy; r[4] = dw; r[5] = dh;
      r[6] = tc;
      r[7] = 0.0f;
    }
    return;
  }

  // ---- per-cell path ----
  // stage targets in corner form: (x-w/2, y-h/2, x+w/2, y+h/2), area-or-(-1)
  for (int i = tid; i < Bn * Kn; i += 256) {
    const float* tp = tgt + (size_t)i * 5;
    float tx = tp[0], ty = tp[1], tw = tp[2], th = tp[3], tc = tp[4];
    float hw_ = tw * 0.5f, hh_ = th * 0.5f;
    tga[i] = make_float4(tx - hw_, ty - hh_, tx + hw_, ty + hh_);
    tgb[i] = (tx + ty + tw + th + tc > 0.0f) ? tw * th : -1.0f;
  }
  if (tid < 48) { ls1[tid] = 0.0f; ls2[tid] = 0.0f; lhp[tid] = 0.0f; }
  if (tid == 0) lcnt = 0;
  __syncthreads();

  int g = blockIdx.x * 256 + tid;
  if (g < NTOT) {
    int s, H, HW, base, b, a, hw;
    decode_cell(g, s, H, HW, base, b, a, hw);
    int W = H;
    float Wf = (float)W, W2 = Wf * Wf;
    const float* o = (s == 0) ? o0 : (s == 1) ? o1 : o2;
    int x = hw % W, y = hw / W;
    int aoff = 6 - 3 * s;
    float aw = anc[(aoff + a) * 2], ah = anc[(aoff + a) * 2 + 1];
    int ob = (b * 255 + a * 85) * HW + hw;
    float px = sigf(o[ob]) + (float)x;
    float py = sigf(o[ob + HW]) + (float)y;
    float pw = __expf(o[ob + 2 * HW]) * aw;
    float ph = __expf(o[ob + 3 * HW]) * ah;
    float conf = sigf(o[ob + 4 * HW]);
    float pxl = px - pw * 0.5f, pxr = px + pw * 0.5f;
    float pyl = py - ph * 0.5f, pyr = py + ph * 0.5f;
    float parea = pw * ph;
    float bi = -1.0f, bu = 1.0f;           // best (inter, union); mi = bi/bu
    const float4* ca = &tga[b * Kn];
    const float*  cb = &tgb[b * Kn];
    for (int k = 0; k < Kn; k++) {
      float fa = cb[k];
      if (fa >= 0.0f) {
        float4 c = ca[k];
        float tlx = fmaxf(pxl, c.x * Wf);
        float tly = fmaxf(pyl, c.y * Wf);
        float brx = fminf(pxr, c.z * Wf);
        float bry = fminf(pyr, c.w * Wf);
        float w = fmaxf(brx - tlx, 0.0f);
        float h = fmaxf(bry - tly, 0.0f);
        float inter = w * h;
        float uni = parea + fa * W2 - inter;
        // inter/uni > bi/bu  <=>  inter*bu > bi*uni  (uni,bu > 0)
        if (inter * bu > bi * uni) { bi = inter; bu = uni; }
      }
    }
    float mi = bi / bu;                    // -1 when no valid target
    ws[MIOU_OFF + g] = mi;
    int key = s * 16 + b;
    float c2 = conf * conf;
    atomicAdd(&ls1[key], c2);
    if (mi >= IGN) atomicAdd(&ls2[key], c2);
    if (mi > IGN) lhp[key] = 1.0f;         // benign race, all write 1.0
  }
  __syncthreads();
  // compact export of touched keys (<= 3 per block, 4 slots reserved)
  if (tid < 48 && ls1[tid] != 0.0f) {
    int p = atomicAdd(&lcnt, 1);
    float* e = ws + EXPD_OFF + (size_t)blockIdx.x * 16 + p * 4;
    e[0] = __int_as_float(tid);
    e[1] = ls1[tid];
    e[2] = ls2[tid];
    e[3] = lhp[tid];
  }
  __syncthreads();
  if (tid == 0) ((int*)ws)[EXPC_OFF + blockIdx.x] = lcnt;
}

// ---- kFinal: one WAVE per winner record; atomic-accumulate; the LAST block
//      (device-scope ticket) adds the noobj fixup and writes the output ----
__global__ __launch_bounds__(256) void kFinal(const float* __restrict__ o0,
                                              const float* __restrict__ o1,
                                              const float* __restrict__ o2,
                                              float* __restrict__ ws,
                                              float* __restrict__ out) {
  __shared__ float wsum[4];
  __shared__ int amLast;
  __shared__ float S1L[48], S2L[48], HPL[48];
  int tid = threadIdx.x;
  int lane = tid & 63;
  int idx = (blockIdx.x * 256 + tid) >> 6;   // record id, 0..2399
  float contrib = 0.0f;

  const float* r = ws + REC_OFF + (size_t)idx * 8;
  if (r[0] != 0.0f) {
    int g = __float_as_int(r[1]);
    int s, H, HW, base, b, a, hw;
    decode_cell(g, s, H, HW, base, b, a, hw);
    const float* o = (s == 0) ? o0 : (s == 1) ? o1 : o2;
    int ob = (b * 255 + a * 85) * HW + hw;
    // class LSE: lane l covers c = l and c = l + 64
    float l1 = (lane < NCn) ? o[ob + (5 + lane) * HW] : -1e30f;
    float l2 = (lane + 64 < NCn) ? o[ob + (5 + lane + 64) * HW] : -1e30f;
    float mx = fmaxf(l1, l2);
    for (int off = 32; off > 0; off >>= 1) mx = fmaxf(mx, __shfl_xor(mx, off));
    float sm = __expf(l1 - mx) + __expf(l2 - mx);
    for (int off = 32; off > 0; off >>= 1) sm += __shfl_xor(sm, off);
    if (lane == 0) {
      float lse = mx + __logf(sm);
      int cls = (int)r[6];
      float tgtl = o[ob + (5 + cls) * HW];
      float d0 = sigf(o[ob]) - r[2];
      float d1 = sigf(o[ob + HW]) - r[3];
      float d2 = __expf(o[ob + 2 * HW]) - r[4];
      float d3 = __expf(o[ob + 3 * HW]) - r[5];
      float box = d0 * d0 + d1 * d1 + d2 * d2 + d3 * d3;
      float conf = sigf(o[ob + 4 * HW]);
      float mi = ws[MIOU_OFF + g];            // == obj_iou at winner slot
      // winner => num_obj>0. basem: mi>IGN => has_pos certainly 1 => 0;
      // mi<IGN => 1 regardless of has_pos; mi==IGN exactly: measure-zero.
      float basem = (mi >= IGN) ? 0.0f : 1.0f;
      float vb = conf * basem;                // remove kMain's base noobj term
      float dv = 5.0f * (conf - mi);          // OBJ_SCALE = 5
      float iouc = dv * dv - vb * vb;
      contrib += box * W_BOX + iouc * W_IOU + (lse - tgtl) * W_CLS;
    }
  }

  // wave reduce -> block reduce -> one atomicAdd into the global accumulator
  for (int off = 32; off > 0; off >>= 1) contrib += __shfl_down(contrib, off);
  if (lane == 0) wsum[tid >> 6] = contrib;
  __syncthreads();
  if (tid == 0) {
    float t = wsum[0] + wsum[1] + wsum[2] + wsum[3];
    if (t != 0.0f) atomicAdd(&ws[ACC_OFF], t);
    __threadfence();
    int ticket = atomicAdd((int*)ws + CNT_OFF, 1);
    amLast = (ticket == NBLK_F - 1);
  }
  __syncthreads();
  if (!amLast) return;

  // ---- last block: noobj fixup from kMain exports + final store ----
  __threadfence();
  if (tid < 48) { S1L[tid] = 0.0f; S2L[tid] = 0.0f; HPL[tid] = 0.0f; }
  __syncthreads();
  for (int bid = tid; bid < NBLK_A; bid += 256) {
    int cnt = ((const int*)ws)[EXPC_OFF + bid];
    const float* e = ws + EXPD_OFF + (size_t)bid * 16;
    for (int j = 0; j < cnt; j++) {
      int key = __float_as_int(e[j * 4]);
      atomicAdd(&S1L[key], e[j * 4 + 1]);
      atomicAdd(&S2L[key], e[j * 4 + 2]);
      if (e[j * 4 + 3] != 0.0f) HPL[key] = 1.0f;  // benign race
    }
  }
  __syncthreads();
  float c = 0.0f;
  if (tid < 48) {
    int b = tid & 15;
    int nobj = ((const int*)ws)[NO_OFF + b];
    if (nobj > 0)
      c += ((HPL[tid] > 0.0f) ? (S1L[tid] - S2L[tid]) : S1L[tid]) * W_IOU;
  }
  for (int off = 32; off > 0; off >>= 1) c += __shfl_down(c, off);
  if (lane == 0) wsum[tid >> 6] = c;
  __syncthreads();
  if (tid == 0) {
    float fix = wsum[0] + wsum[1] + wsum[2] + wsum[3];
    float acc = atomicAdd(&ws[ACC_OFF], 0.0f);  // coherent read of full sum
    out[0] = acc + fix;
  }
}

extern "C" void kernel_launch(void* const* d_in, const int* in_sizes, int n_in,
                              void* d_out, int out_size, void* d_ws, size_t ws_size,
                              hipStream_t stream) {
  const float* o0  = (const float*)d_in[0];
  const float* o1  = (const float*)d_in[1];
  const float* o2  = (const float*)d_in[2];
  const float* tgt = (const float*)d_in[3];
  const float* anc = (const float*)d_in[4];
  float* ws  = (float*)d_ws;
  float* out = (float*)d_out;

  kMain<<<NBLK_A + NBLK_ASSIGN, 256, 0, stream>>>(o0, o1, o2, tgt, anc, ws);
  kFinal<<<NBLK_F, 256, 0, stream>>>(o0, o1, o2, ws, out);
}

// Round 7
// 112.970 us; speedup vs baseline: 1.1258x; 1.1258x over previous
//
#include <hip/hip_runtime.h>

// ---------------- problem constants (from setup_inputs) ----------------
static constexpr int Bn = 16, Kn = 50, NCn = 80;
// scales: s=0 -> o1 (13x13, anchors[6:9]), s=1 -> o2 (26x26, anchors[3:6]),
//         s=2 -> o3 (52x52, anchors[0:3])
static constexpr int NTOT = 16 * 3 * (169 + 676 + 2704);   // 170352 cells
static constexpr int NBLK_A = (NTOT + 255) / 256;          // 666
static constexpr int NBLK_ASSIGN = 12;                     // 48 waves, 1 per (s,b)
static constexpr int NREC = 3 * Bn * Kn;                   // 2400 records
static constexpr int NBLK_F = NREC / 16;                   // 150 blocks, 16 waves ea
// ws layout (float/int elements) — NOTHING needs pre-zeroing (poison-safe):
static constexpr int MIOU_OFF = 0;                 // 170352 floats, all written
static constexpr int NO_OFF   = 170352;            // 16 ints, all written
static constexpr int REC_OFF  = 170368;            // 2400 x 8 floats, all written
static constexpr int EXPC_OFF = 189568;            // 666 ints: export count/block
static constexpr int EXPD_OFF = 190240;            // 666 x 16 floats: exports
static constexpr int PARTF_OFF = 200896;           // 150 floats: kFinal partials
static constexpr float IGN = 0.7f;
static constexpr float W_BOX = 1.0f / 96.0f;  // 0.5 / (B*3)
static constexpr float W_IOU = 1.0f / 96.0f;  // 0.5 / (B*3)
static constexpr float W_CLS = 1.0f / 48.0f;  // 1.0 / (B*3)

__device__ __forceinline__ float sigf(float x) { return 1.0f / (1.0f + __expf(-x)); }

__device__ __forceinline__ float iou_box(float ax, float ay, float aw, float ah,
                                         float bx, float by, float bw, float bh) {
  float tlx = fmaxf(ax - aw * 0.5f, bx - bw * 0.5f);
  float tly = fmaxf(ay - ah * 0.5f, by - bh * 0.5f);
  float brx = fminf(ax + aw * 0.5f, bx + bw * 0.5f);
  float bry = fminf(ay + ah * 0.5f, by + bh * 0.5f);
  float w = fmaxf(brx - tlx, 0.0f);
  float h = fmaxf(bry - tly, 0.0f);
  float inter = w * h;
  float uni = aw * ah + bw * bh - inter;
  return inter / uni;
}

__device__ __forceinline__ void decode_cell(int g, int& s, int& H, int& HW,
                                            int& base, int& b, int& a, int& hw) {
  if (g < 8112)       { s = 0; H = 13; HW = 169;  base = 0; }
  else if (g < 40560) { s = 1; H = 26; HW = 676;  base = 8112; }
  else                { s = 2; H = 52; HW = 2704; base = 40560; }
  int local = g - base;
  hw = local % HW;
  int t = local / HW;
  a = t % 3;
  b = t / 3;
}

// ---- kMain ----
// blocks [0, NBLK_A): per-cell max-IoU (corner-form targets, cross-mult max,
//   one div) + LDS noobj partials exported compacted per block.
// blocks [NBLK_A, NBLK_A+12): target assignment, one wave per (scale,batch).
__global__ __launch_bounds__(256) void kMain(const float* __restrict__ o0,
                                             const float* __restrict__ o1,
                                             const float* __restrict__ o2,
                                             const float* __restrict__ tgt,
                                             const float* __restrict__ anc,
                                             float* __restrict__ ws) {
  __shared__ float tg[Bn * Kn * 5];      // raw targets (assignment path)
  __shared__ float4 tga[Bn * Kn];        // corner-form  (per-cell path)
  __shared__ float  tgb[Bn * Kn];        // valid? area : -1
  __shared__ float ls1[48], ls2[48], lhp[48];
  __shared__ int lcnt;
  int tid = threadIdx.x;

  if (blockIdx.x >= NBLK_A) {
    // ---- parallel target assignment ----
    for (int i = tid; i < Bn * Kn * 5; i += 256) tg[i] = tgt[i];
    __syncthreads();
    int wv = (blockIdx.x - NBLK_A) * 4 + (tid >> 6);  // 0..47 = (s,b)
    int lane = tid & 63;
    int s = wv / 16, b = wv % 16;
    int H, HW, base;
    if (s == 0)      { H = 13; HW = 169;  base = 0; }
    else if (s == 1) { H = 26; HW = 676;  base = 8112; }
    else             { H = 52; HW = 2704; base = 40560; }
    int W = H;
    int aoff = 6 - 3 * s;
    float aw0 = anc[aoff * 2],       ah0 = anc[aoff * 2 + 1];
    float aw1 = anc[(aoff + 1) * 2], ah1 = anc[(aoff + 1) * 2 + 1];
    float aw2 = anc[(aoff + 2) * 2], ah2 = anc[(aoff + 2) * 2 + 1];

    bool valid = false;
    int gslot = -1 - lane;                  // unique sentinel for invalid lanes
    float dx = 0, dy = 0, dw = 0, dh = 0, tc = 0;
    if (lane < Kn) {
      const float* tp = &tg[(b * Kn + lane) * 5];
      float tx = tp[0], ty = tp[1], tw = tp[2], th = tp[3];
      tc = tp[4];
      if (tx + ty + tw + th + tc > 0.0f) {
        valid = true;
        float gx = tx * W, gy = ty * H, gw = tw * W, gh = th * H;
        int cx = (int)floorf(gx); cx = min(max(cx, 0), W - 1);
        int cy = (int)floorf(gy); cy = min(max(cy, 0), H - 1);
        float ccx = cx + 0.5f, ccy = cy + 0.5f;
        float i0 = iou_box(ccx, ccy, aw0, ah0, gx, gy, gw, gh);
        float i1 = iou_box(ccx, ccy, aw1, ah1, gx, gy, gw, gh);
        float i2 = iou_box(ccx, ccy, aw2, ah2, gx, gy, gw, gh);
        int astar = 0; float bi = i0;
        if (i1 > bi) { bi = i1; astar = 1; }   // strict > == argmax first-max
        if (i2 > bi) { bi = i2; astar = 2; }
        float raw = (astar == 0) ? aw0 : (astar == 1) ? aw1 : aw2;
        float rah = (astar == 0) ? ah0 : (astar == 1) ? ah1 : ah2;
        gslot = base + (b * 3 + astar) * HW + cy * W + cx;
        dx = gx - (float)cx;
        dy = gy - (float)cy;
        dw = gw / raw;
        dh = gh / rah;
      }
    }
    // winner = valid and no valid lane k2 > lane targeting the same slot
    // (== jax segment_max over global rank: slots never collide across b/s)
    bool win = valid;
    for (int k2 = 1; k2 < Kn; k2++) {
      int other = __shfl(gslot, k2);
      if (k2 > lane && other == gslot) win = false;
    }
    unsigned long long bal = __ballot(valid);
    if (lane == 0 && s == 0) ((int*)ws)[NO_OFF + b] = (int)__popcll(bal);
    if (lane < Kn) {
      float* r = ws + REC_OFF + (size_t)(wv * Kn + lane) * 8;
      r[0] = win ? 1.0f : 0.0f;
      r[1] = __int_as_float(gslot);
      r[2] = dx; r[3] = dy; r[4] = dw; r[5] = dh;
      r[6] = tc;
      r[7] = 0.0f;
    }
    return;
  }

  // ---- per-cell path ----
  // stage targets in corner form: (x-w/2, y-h/2, x+w/2, y+h/2), area-or-(-1)
  for (int i = tid; i < Bn * Kn; i += 256) {
    const float* tp = tgt + (size_t)i * 5;
    float tx = tp[0], ty = tp[1], tw = tp[2], th = tp[3], tc = tp[4];
    float hw_ = tw * 0.5f, hh_ = th * 0.5f;
    tga[i] = make_float4(tx - hw_, ty - hh_, tx + hw_, ty + hh_);
    tgb[i] = (tx + ty + tw + th + tc > 0.0f) ? tw * th : -1.0f;
  }
  if (tid < 48) { ls1[tid] = 0.0f; ls2[tid] = 0.0f; lhp[tid] = 0.0f; }
  if (tid == 0) lcnt = 0;
  __syncthreads();

  int g = blockIdx.x * 256 + tid;
  if (g < NTOT) {
    int s, H, HW, base, b, a, hw;
    decode_cell(g, s, H, HW, base, b, a, hw);
    int W = H;
    float Wf = (float)W, W2 = Wf * Wf;
    const float* o = (s == 0) ? o0 : (s == 1) ? o1 : o2;
    int x = hw % W, y = hw / W;
    int aoff = 6 - 3 * s;
    float aw = anc[(aoff + a) * 2], ah = anc[(aoff + a) * 2 + 1];
    int ob = (b * 255 + a * 85) * HW + hw;
    float px = sigf(o[ob]) + (float)x;
    float py = sigf(o[ob + HW]) + (float)y;
    float pw = __expf(o[ob + 2 * HW]) * aw;
    float ph = __expf(o[ob + 3 * HW]) * ah;
    float conf = sigf(o[ob + 4 * HW]);
    float pxl = px - pw * 0.5f, pxr = px + pw * 0.5f;
    float pyl = py - ph * 0.5f, pyr = py + ph * 0.5f;
    float parea = pw * ph;
    float bi = -1.0f, bu = 1.0f;           // best (inter, union); mi = bi/bu
    const float4* ca = &tga[b * Kn];
    const float*  cb = &tgb[b * Kn];
    for (int k = 0; k < Kn; k++) {
      float fa = cb[k];
      if (fa >= 0.0f) {
        float4 c = ca[k];
        float tlx = fmaxf(pxl, c.x * Wf);
        float tly = fmaxf(pyl, c.y * Wf);
        float brx = fminf(pxr, c.z * Wf);
        float bry = fminf(pyr, c.w * Wf);
        float w = fmaxf(brx - tlx, 0.0f);
        float h = fmaxf(bry - tly, 0.0f);
        float inter = w * h;
        float uni = parea + fa * W2 - inter;
        // inter/uni > bi/bu  <=>  inter*bu > bi*uni  (uni,bu > 0)
        if (inter * bu > bi * uni) { bi = inter; bu = uni; }
      }
    }
    float mi = bi / bu;                    // -1 when no valid target
    ws[MIOU_OFF + g] = mi;
    int key = s * 16 + b;
    float c2 = conf * conf;
    atomicAdd(&ls1[key], c2);
    if (mi >= IGN) atomicAdd(&ls2[key], c2);
    if (mi > IGN) lhp[key] = 1.0f;         // benign race, all write 1.0
  }
  __syncthreads();
  // compact export of touched keys (<= 3 per block, 4 slots reserved)
  if (tid < 48 && ls1[tid] != 0.0f) {
    int p = atomicAdd(&lcnt, 1);
    float* e = ws + EXPD_OFF + (size_t)blockIdx.x * 16 + p * 4;
    e[0] = __int_as_float(tid);
    e[1] = ls1[tid];
    e[2] = ls2[tid];
    e[3] = lhp[tid];
  }
  __syncthreads();
  if (tid == 0) ((int*)ws)[EXPC_OFF + blockIdx.x] = lcnt;
}

// ---- kFinal: one WAVE per winner record, 16 waves/block; plain partial store ----
__global__ __launch_bounds__(1024) void kFinal(const float* __restrict__ o0,
                                               const float* __restrict__ o1,
                                               const float* __restrict__ o2,
                                               float* __restrict__ ws) {
  __shared__ float wsum[16];
  int tid = threadIdx.x;
  int lane = tid & 63;
  int idx = (blockIdx.x * 1024 + tid) >> 6;   // record id, 0..2399
  float contrib = 0.0f;

  const float* r = ws + REC_OFF + (size_t)idx * 8;
  if (r[0] != 0.0f) {
    int g = __float_as_int(r[1]);
    int s, H, HW, base, b, a, hw;
    decode_cell(g, s, H, HW, base, b, a, hw);
    const float* o = (s == 0) ? o0 : (s == 1) ? o1 : o2;
    int ob = (b * 255 + a * 85) * HW + hw;
    // class LSE: lane l covers c = l and c = l + 64
    float l1 = (lane < NCn) ? o[ob + (5 + lane) * HW] : -1e30f;
    float l2 = (lane + 64 < NCn) ? o[ob + (5 + lane + 64) * HW] : -1e30f;
    float mx = fmaxf(l1, l2);
    for (int off = 32; off > 0; off >>= 1) mx = fmaxf(mx, __shfl_xor(mx, off));
    float sm = __expf(l1 - mx) + __expf(l2 - mx);
    for (int off = 32; off > 0; off >>= 1) sm += __shfl_xor(sm, off);
    if (lane == 0) {
      float lse = mx + __logf(sm);
      int cls = (int)r[6];
      float tgtl = o[ob + (5 + cls) * HW];
      float d0 = sigf(o[ob]) - r[2];
      float d1 = sigf(o[ob + HW]) - r[3];
      float d2 = __expf(o[ob + 2 * HW]) - r[4];
      float d3 = __expf(o[ob + 3 * HW]) - r[5];
      float box = d0 * d0 + d1 * d1 + d2 * d2 + d3 * d3;
      float conf = sigf(o[ob + 4 * HW]);
      float mi = ws[MIOU_OFF + g];            // == obj_iou at winner slot
      // winner => num_obj>0. basem: mi>IGN => has_pos certainly 1 => 0;
      // mi<IGN => 1 regardless of has_pos; mi==IGN exactly: measure-zero.
      float basem = (mi >= IGN) ? 0.0f : 1.0f;
      float vb = conf * basem;                // remove kMain's base noobj term
      float dv = 5.0f * (conf - mi);          // OBJ_SCALE = 5
      float iouc = dv * dv - vb * vb;
      contrib += box * W_BOX + iouc * W_IOU + (lse - tgtl) * W_CLS;
    }
  }

  // wave reduce -> block partial (unconditional plain store, poison-safe)
  for (int off = 32; off > 0; off >>= 1) contrib += __shfl_down(contrib, off);
  if (lane == 0) wsum[tid >> 6] = contrib;
  __syncthreads();
  if (tid == 0) {
    float t = 0.0f;
    #pragma unroll
    for (int i = 0; i < 16; i++) t += wsum[i];
    ws[PARTF_OFF + blockIdx.x] = t;
  }
}

// ---- kSum: single block — noobj fixup from exports + sum all partials ----
__global__ __launch_bounds__(256) void kSum(const float* __restrict__ ws,
                                            float* __restrict__ out) {
  __shared__ float S1L[48], S2L[48], HPL[48];
  __shared__ float bsum[4];
  int tid = threadIdx.x;
  if (tid < 48) { S1L[tid] = 0.0f; S2L[tid] = 0.0f; HPL[tid] = 0.0f; }
  __syncthreads();
  for (int bid = tid; bid < NBLK_A; bid += 256) {
    int cnt = ((const int*)ws)[EXPC_OFF + bid];
    const float* e = ws + EXPD_OFF + (size_t)bid * 16;
    for (int j = 0; j < cnt; j++) {
      int key = __float_as_int(e[j * 4]);
      atomicAdd(&S1L[key], e[j * 4 + 1]);
      atomicAdd(&S2L[key], e[j * 4 + 2]);
      if (e[j * 4 + 3] != 0.0f) HPL[key] = 1.0f;  // benign race
    }
  }
  __syncthreads();
  float c = 0.0f;
  if (tid < 48) {
    int b = tid & 15;
    int nobj = ((const int*)ws)[NO_OFF + b];
    if (nobj > 0)
      c += ((HPL[tid] > 0.0f) ? (S1L[tid] - S2L[tid]) : S1L[tid]) * W_IOU;
  }
  for (int i = tid; i < NBLK_F; i += 256) c += ws[PARTF_OFF + i];
  for (int off = 32; off > 0; off >>= 1) c += __shfl_down(c, off);
  if ((tid & 63) == 0) bsum[tid >> 6] = c;
  __syncthreads();
  if (tid == 0) out[0] = bsum[0] + bsum[1] + bsum[2] + bsum[3];
}

extern "C" void kernel_launch(void* const* d_in, const int* in_sizes, int n_in,
                              void* d_out, int out_size, void* d_ws, size_t ws_size,
                              hipStream_t stream) {
  const float* o0  = (const float*)d_in[0];
  const float* o1  = (const float*)d_in[1];
  const float* o2  = (const float*)d_in[2];
  const float* tgt = (const float*)d_in[3];
  const float* anc = (const float*)d_in[4];
  float* ws  = (float*)d_ws;
  float* out = (float*)d_out;

  kMain<<<NBLK_A + NBLK_ASSIGN, 256, 0, stream>>>(o0, o1, o2, tgt, anc, ws);
  kFinal<<<NBLK_F, 1024, 0, stream>>>(o0, o1, o2, ws);
  kSum<<<1, 256, 0, stream>>>(ws, out);
}